// Round 3
// baseline (450.711 us; speedup 1.0000x reference)
//
#include <hip/hip_runtime.h>
#include <hip/hip_cooperative_groups.h>

namespace cg = cooperative_groups;

#define H 2048

// inter-phase scratch (device globals; fully rewritten every call before read)
__device__ __align__(16) float g_p1[4 * H];   // layer-1 recurrent partial + both biases
__device__ __align__(16) float g_h0[H];       // layer-0 new h
__device__ __align__(16) float g_h1[H];       // layer-1 new h
__device__ __align__(16) float g_hid[13 * 64];// head hidden activations

__device__ const int c_HO[13]  = {5,1,1,1,1,1,1,1,9,1,3,1,1};
__device__ const int c_OFF[13] = {0,5,6,7,8,9,10,11,12,21,22,25,26};

__device__ __forceinline__ float sg(float x) { return 1.f / (1.f + __expf(-x)); }

__device__ __forceinline__ float wred(float x) {
    #pragma unroll
    for (int o = 32; o > 0; o >>= 1) x += __shfl_down(x, o);
    return x;
}

// All 4 gate rows (q*H + j) of a 4H x H row-major W, dotted against an LDS vector.
// All 32 float4 loads are issued before the FMA block: 32 KB per wave in flight.
__device__ __forceinline__ void dot4(const float* __restrict__ W, int j,
                                     const float* __restrict__ vecLDS, int lane,
                                     float acc[4]) {
    float4 wv[4][8];
    #pragma unroll
    for (int q = 0; q < 4; q++) {
        const float4* wr = reinterpret_cast<const float4*>(W + (long)(q * H + j) * H);
        #pragma unroll
        for (int i = 0; i < 8; i++) wv[q][i] = wr[i * 64 + lane];
    }
    #pragma unroll
    for (int i = 0; i < 8; i++) {
        float4 hv = reinterpret_cast<const float4*>(vecLDS)[i * 64 + lane];
        #pragma unroll
        for (int q = 0; q < 4; q++) {
            acc[q] = fmaf(wv[q][i].x, hv.x, acc[q]);
            acc[q] = fmaf(wv[q][i].y, hv.y, acc[q]);
            acc[q] = fmaf(wv[q][i].z, hv.z, acc[q]);
            acc[q] = fmaf(wv[q][i].w, hv.w, acc[q]);
        }
    }
}

__global__ __launch_bounds__(256) void fused(
    const float* __restrict__ lap, const int* __restrict__ idx,
    const float* __restrict__ h_s, const float* __restrict__ c_s,
    const float* __restrict__ e_team, const float* __restrict__ e_trk,
    const float* __restrict__ e_drv, const float* __restrict__ e_cmp,
    const float* __restrict__ Wih0, const float* __restrict__ Whh0,
    const float* __restrict__ bih0, const float* __restrict__ bhh0,
    const float* __restrict__ Wih1, const float* __restrict__ Whh1,
    const float* __restrict__ bih1, const float* __restrict__ bhh1,
    const float* __restrict__ ln_g, const float* __restrict__ ln_b,
    const float* __restrict__ W1, const float* __restrict__ b1,
    const float* __restrict__ W2, const float* __restrict__ b2,
    float* __restrict__ out)
{
    __shared__ float vec[2 * H];   // [0:H) = layer-0 vector, [H:2H) = layer-1 vector
    __shared__ float xsh[96];
    __shared__ float red[8];
    __shared__ float mvs[2];
    cg::grid_group grid = cg::this_grid();

    int tid = threadIdx.x, w = tid >> 6, lane = tid & 63;
    int nw = gridDim.x * 4;            // total waves in grid
    int gw = blockIdx.x * 4 + w;       // global wave id

    // ---- stage h_prev for BOTH layers (16 KB) + the 92-wide input x ----
    {
        float4* v4 = reinterpret_cast<float4*>(vec);
        const float4* s4 = reinterpret_cast<const float4*>(h_s);
        #pragma unroll
        for (int i = 0; i < 4; i++) v4[tid + i * 256] = s4[tid + i * 256];
        if (tid < 92) {
            float v;
            if (tid < 60)      v = lap[tid];
            else if (tid < 68) v = e_team[idx[3] * 8 + tid - 60];
            else if (tid < 76) v = e_trk [idx[2] * 8 + tid - 68];
            else if (tid < 84) v = e_drv [idx[1] * 8 + tid - 76];
            else               v = e_cmp [idx[0] * 8 + tid - 84];
            xsh[tid] = v;
        }
    }
    __syncthreads();

    // ---- Phase A: layer-0 cells (units 0..2047) + Whh1 partials (2048..4095) ----
    for (int u = gw; u < 4096; u += nw) {
        float acc[4] = {0.f, 0.f, 0.f, 0.f};
        if (u < 2048) {
            int j = u;
            dot4(Whh0, j, vec, lane, acc);
            #pragma unroll
            for (int q = 0; q < 4; q++) {          // 92-wide input dot
                const float* wr = Wih0 + (long)(q * H + j) * 92;
                float p = xsh[lane] * wr[lane];
                if (lane < 28) p = fmaf(xsh[lane + 64], wr[lane + 64], p);
                acc[q] += p;
            }
            float bs[4];
            #pragma unroll
            for (int q = 0; q < 4; q++) bs[q] = bih0[q * H + j] + bhh0[q * H + j];
            #pragma unroll
            for (int q = 0; q < 4; q++) acc[q] = wred(acc[q]);
            if (lane == 0) {
                float gi = acc[0] + bs[0], gf = acc[1] + bs[1];
                float gg = acc[2] + bs[2], go = acc[3] + bs[3];
                float cp = c_s[j];
                float cn = sg(gf) * cp + sg(gi) * tanhf(gg);
                float hn = sg(go) * tanhf(cn);
                out[j]         = hn;   // new_h[0]
                out[2 * H + j] = cn;   // new_c[0]
                g_h0[j] = hn;
            }
        } else {
            int j = u - 2048;
            dot4(Whh1, j, vec + H, lane, acc);
            float bs[4];
            #pragma unroll
            for (int q = 0; q < 4; q++) bs[q] = bih1[q * H + j] + bhh1[q * H + j];
            #pragma unroll
            for (int q = 0; q < 4; q++) acc[q] = wred(acc[q]);
            if (lane == 0) {
                #pragma unroll
                for (int q = 0; q < 4; q++) g_p1[q * H + j] = acc[q] + bs[q];
            }
        }
    }
    __threadfence();
    grid.sync();

    // ---- Phase B: layer-1 cells (Wih1 @ h0_new + g_p1) ----
    {
        float4* v4 = reinterpret_cast<float4*>(vec);
        const float4* s4 = reinterpret_cast<const float4*>(g_h0);
        #pragma unroll
        for (int i = 0; i < 2; i++) v4[tid + i * 256] = s4[tid + i * 256];
    }
    __syncthreads();
    for (int c = gw; c < 2048; c += nw) {
        float acc[4] = {0.f, 0.f, 0.f, 0.f};
        dot4(Wih1, c, vec, lane, acc);
        float ps[4];
        #pragma unroll
        for (int q = 0; q < 4; q++) ps[q] = g_p1[q * H + c];
        #pragma unroll
        for (int q = 0; q < 4; q++) acc[q] = wred(acc[q]);
        if (lane == 0) {
            float gi = acc[0] + ps[0], gf = acc[1] + ps[1];
            float gg = acc[2] + ps[2], go = acc[3] + ps[3];
            float cp = c_s[H + c];
            float cn = sg(gf) * cp + sg(gi) * tanhf(gg);
            float hn = sg(go) * tanhf(cn);
            out[H + c]     = hn;   // new_h[1]
            out[3 * H + c] = cn;   // new_c[1]
            g_h1[c] = hn;
        }
    }
    __threadfence();
    grid.sync();

    // ---- Phase C: LayerNorm (redundant per participating block) + head hidden ----
    bool cwork = ((blockIdx.x * 4) < 832) || (nw < 832);
    if (cwork) {
        const float4* s4 = reinterpret_cast<const float4*>(g_h1);
        float4* v4 = reinterpret_cast<float4*>(vec);
        float4 h0v = s4[tid], h1v = s4[tid + 256];
        float s  = h0v.x + h0v.y + h0v.z + h0v.w + h1v.x + h1v.y + h1v.z + h1v.w;
        float s2 = h0v.x*h0v.x + h0v.y*h0v.y + h0v.z*h0v.z + h0v.w*h0v.w
                 + h1v.x*h1v.x + h1v.y*h1v.y + h1v.z*h1v.z + h1v.w*h1v.w;
        s = wred(s); s2 = wred(s2);
        if (lane == 0) { red[w] = s; red[4 + w] = s2; }
        __syncthreads();
        if (tid == 0) {
            float ts = red[0] + red[1] + red[2] + red[3];
            float t2 = red[4] + red[5] + red[6] + red[7];
            float mu = ts / (float)H;
            float var = t2 / (float)H - mu * mu;
            mvs[0] = mu; mvs[1] = rsqrtf(var + 1e-5f);
        }
        __syncthreads();
        float mu = mvs[0], rs = mvs[1];
        const float4* g4 = reinterpret_cast<const float4*>(ln_g);
        const float4* b4 = reinterpret_cast<const float4*>(ln_b);
        float4 ga = g4[tid], gb = g4[tid + 256];
        float4 ba = b4[tid], bb = b4[tid + 256];
        float4 o0, o1;
        o0.x = (h0v.x - mu) * rs * ga.x + ba.x;  o0.y = (h0v.y - mu) * rs * ga.y + ba.y;
        o0.z = (h0v.z - mu) * rs * ga.z + ba.z;  o0.w = (h0v.w - mu) * rs * ga.w + ba.w;
        o1.x = (h1v.x - mu) * rs * gb.x + bb.x;  o1.y = (h1v.y - mu) * rs * gb.y + bb.y;
        o1.z = (h1v.z - mu) * rs * gb.z + bb.z;  o1.w = (h1v.w - mu) * rs * gb.w + bb.w;
        v4[tid] = o0; v4[tid + 256] = o1;
        __syncthreads();
        for (int r = gw; r < 832; r += nw) {      // 13 heads x 64 units
            const float4* wr = reinterpret_cast<const float4*>(W1 + (long)r * H);
            float4 wv[8];
            #pragma unroll
            for (int i = 0; i < 8; i++) wv[i] = wr[i * 64 + lane];
            float a = 0.f;
            #pragma unroll
            for (int i = 0; i < 8; i++) {
                float4 hh = reinterpret_cast<const float4*>(vec)[i * 64 + lane];
                a = fmaf(wv[i].x, hh.x, a); a = fmaf(wv[i].y, hh.y, a);
                a = fmaf(wv[i].z, hh.z, a); a = fmaf(wv[i].w, hh.w, a);
            }
            a = wred(a);
            if (lane == 0) {
                float t = a + b1[r];
                g_hid[r] = t > 0.f ? t : 0.f;
            }
        }
    }
    __threadfence();
    grid.sync();

    // ---- Phase D: head output layer (117 tiny dots, one per wave) ----
    for (int r = gw; r < 117; r += nw) {
        int k = r / 9, p = r - k * 9;
        if (p < c_HO[k]) {
            float wv = W2[((long)(k * 9 + p)) * 64 + lane];
            float hh = g_hid[k * 64 + lane];
            float a = wred(wv * hh);
            if (lane == 0) out[4 * H + c_OFF[k] + p] = a + b2[k * 9 + p];
        }
    }
}

extern "C" void kernel_launch(void* const* d_in, const int* in_sizes, int n_in,
                              void* d_out, int out_size, void* d_ws, size_t ws_size,
                              hipStream_t stream) {
    // grid sized once from the occupancy API so the cooperative launch always fits;
    // all phases are grid-stride so any grid size is correct.
    static int grid = 0;
    if (grid == 0) {
        int nb = 0;
        if (hipOccupancyMaxActiveBlocksPerMultiprocessor(&nb, fused, 256, 0) != hipSuccess || nb <= 0)
            nb = 2;  // conservative fallback: 2 blocks/CU certainly fits (34 KB LDS, 512 thr)
        long cap = (long)nb * 256;   // 256 CUs on MI355X
        grid = cap < 1024 ? (int)cap : 1024;
    }

    void* in22[22];
    for (int i = 0; i < 22; i++) in22[i] = d_in[i];
    void* outp = d_out;
    void* args[23];
    for (int i = 0; i < 22; i++) args[i] = &in22[i];
    args[22] = &outp;

    hipLaunchCooperativeKernel(fused, dim3(grid), dim3(256), args, 0, stream);
}